// Round 16
// baseline (1632.526 us; speedup 1.0000x reference)
//
#include <hip/hip_runtime.h>
#include <hip/hip_fp16.h>

typedef unsigned short u16;
typedef unsigned int   u32;

#define BB 4
#define LL 2048
#define DD 256
#define VV 240
#define NLAYERS 6

static constexpr long BLD = (long)BB * LL * DD;   // 2,097,152
static constexpr long LD_ = (long)LL * DD;        // 524,288
static constexpr long LxL = (long)LL * LL;        // 4,194,304
static constexpr long BLL = (long)BB * LxL;       // 16,777,216

typedef _Float16 h8  __attribute__((ext_vector_type(8)));   // MFMA A/B fragment
typedef float  f32x4 __attribute__((ext_vector_type(4)));

__device__ __forceinline__ u16 f2h(float f) {
    _Float16 h = (_Float16)f;
    return __builtin_bit_cast(u16, h);
}
__device__ __forceinline__ float h2f(u16 u) {
    return (float)__builtin_bit_cast(_Float16, u);
}

__device__ __forceinline__ void gl16(const void* g, void* l) {
    __builtin_amdgcn_global_load_lds((const __attribute__((address_space(1))) void*)g,
                                     (__attribute__((address_space(3))) void*)l, 16, 0, 0);
}

// XCD-aware bijective block remap (requires total blocks % 8 == 0).
__device__ __forceinline__ uint3 swz_bid() {
    const int gx = gridDim.x, gy = gridDim.y;
    const int nwg = gx * gy * gridDim.z;
    const int lin = blockIdx.x + gx * (blockIdx.y + gy * blockIdx.z);
    const int q = nwg >> 3;
    const int swz = (lin & 7) * q + (lin >> 3);
    uint3 r;
    r.x = swz % gx;
    const int t2 = swz / gx;
    r.y = t2 % gy;
    r.z = t2 / gy;
    return r;
}

// ---------------- positional encoding precompute: pe[l][i] (batch-independent) ----------------
__global__ __launch_bounds__(256)
void pe_kernel(float* __restrict__ pe)
{
    int idx = blockIdx.x * 256 + threadIdx.x;     // l*DD + i, 524288 total
    int i = idx & (DD - 1);
    int l = idx >> 8;
    float base = (float)l * 1e-5f;
    float p = powf(base, (float)i * (1.0f / (float)DD));
    float ang = p - ((i & 1) ? 0.0f : 1.57079632679489662f);
    pe[idx] = sinf(ang);
}

// ---------------- embedding + pe add (f16 residual stream only) ----------------
__global__ __launch_bounds__(256)
void embed_kernel(const int* __restrict__ tokens, const float* __restrict__ table,
                  const float* __restrict__ pe, u16* __restrict__ xh)
{
    long idx = (long)blockIdx.x * 256 + threadIdx.x;
    if (idx >= BLD) return;
    int i  = (int)(idx & (DD - 1));
    long bl = idx >> 8;
    int l  = (int)(bl & (LL - 1));
    int tok = tokens[bl];
    float v = table[(long)tok * DD + i] + pe[(long)l * DD + i];
    xh[idx] = f2h(v);
}

// ---- merged weight convert+transpose (ALL 10 matrices in one dispatch) ----
// dst[m*lstride + n*256 + k] = f16(W[m][k][n] - Wsub[m][k][n])
struct WcArgs {
    const float* src[10];
    const float* sub[10];       // nullptr -> no subtraction
    u16*         dst[10];
    long         lstride[10];
};

__global__ __launch_bounds__(256)
void wconv_all(WcArgs a)
{
    int blk = blockIdx.x;            // 10 mats * 6 layers * 64 tiles = 3840
    int which = blk / 384;
    int rest  = blk % 384;
    int m  = rest >> 6;
    int ti = (rest >> 3) & 7;        // k tile
    int tj = rest & 7;               // n tile
    const float* src = a.src[which] + (long)m * 65536;
    const float* sub = a.sub[which];
    u16* dst = a.dst[which] + (long)m * a.lstride[which];
    __shared__ float tile[32][33];
    int t = threadIdx.x;
    int c = t & 31, r8 = t >> 5;
    #pragma unroll
    for (int p = 0; p < 4; ++p) {
        int r = r8 + p * 8;
        long off = (long)(ti * 32 + r) * 256 + tj * 32 + c;
        float v = src[off];
        if (sub) v -= sub[(long)m * 65536 + off];
        tile[r][c] = v;
    }
    __syncthreads();
    #pragma unroll
    for (int p = 0; p < 4; ++p) {
        int n = r8 + p * 8;
        dst[(long)(tj * 32 + n) * 256 + ti * 32 + c] = f2h(tile[c][n]);
    }
}

// ---------------- f16 MFMA GEMM, 2-phase double-buffered pipeline (r7-proven) ----------------
// C[M,N] = A[M,K] (row pitch ldA) * B^T  (B stored [N][K], pitch K)
// EPI bits: 1=+bias[n](f32)  2=leaky(0.2)  4=+Cres(f32)  8=write Cf(f32)  16=write Ch(f16)
//   64 = QKEV quad-output: col seg 0->Ch(Q), 1->Ch2(K), 2->Ch3(E), 3->Ch4(V transposed [b][d][l])
//  128 = dual score: bn<2048 uses B  -> Ch(S1);  bn>=2048 uses B2 -> Ch2(QE); pitch LL
//  256 = +residual from f16 buffer (Cres reinterpreted as u16*)
// f16 tile stores are LDS-staged (reusing the dead A/B buffers -> iso-occupancy) and
// emitted as coalesced uint4 rows.
template<int EPI, int BM, int BN>
__global__ __launch_bounds__(256)
void gemm_mfma(const u16* __restrict__ A, const u16* __restrict__ B,
               const u16* __restrict__ B2,
               const float* __restrict__ bias, const float* __restrict__ Cres,
               float* __restrict__ Cf, u16* __restrict__ Ch,
               u16* __restrict__ Ch2, u16* __restrict__ Ch3, u16* __restrict__ Ch4,
               int M, int N, int K, int ldA,
               long sA, long sB, long sC)
{
    constexpr int FM = BM / 32, FN = BN / 32;
    static_assert(2 * BM * 32 + 2 * BN * 32 >= BM * BN, "C-tile must fit in A/B LDS");
    __shared__ u16 smem[2 * BM * 32 + 2 * BN * 32];
    u16* As0 = smem;                     // [2][BM*32]
    u16* Bs0 = smem + 2 * BM * 32;       // [2][BN*32]

    const uint3 bid = swz_bid();           // XCD-contiguous tile chunks (T1)
    const int bz = bid.z;
    A += (long)bz * sA;
    const int bm = bid.y * BM;
    const int bn = bid.x * BN;
    int bnb = bn;                    // column index for B addressing
    const u16* Bp;
    if constexpr (EPI & 128) {
        Bp = (bn >= LL) ? B2 : B;
        if (bn >= LL) bnb = bn - LL;
        Bp += (long)bz * sB;
    } else {
        Bp = B + (long)bz * sB;
    }
    const u16* CresH = (const u16*)Cres;
    if constexpr (EPI & 4)   Cres  += (long)bz * sC;
    if constexpr (EPI & 256) CresH += (long)bz * sC;
    if constexpr (EPI & 8)   Cf    += (long)bz * sC;
    if constexpr ((EPI & 16) && !(EPI & (64 | 128))) Ch += (long)bz * sC;

    const int t = threadIdx.x;
    const int lane = t & 63, wave = t >> 6;
    const int wm = (wave >> 1) * (BM / 2), wn = (wave & 1) * (BN / 2);

    f32x4 acc[FM][FN];
    #pragma unroll
    for (int i = 0; i < FM; ++i)
        #pragma unroll
        for (int j = 0; j < FN; ++j)
            acc[i][j] = (f32x4){0.f, 0.f, 0.f, 0.f};

    const u16* gA0 = A  + (long)(bm  + (t >> 2)) * ldA + (t & 3) * 8;
    const u16* gB0 = Bp + (long)(bnb + (t >> 2)) * K   + (t & 3) * 8;

    const int arow = wm + (lane & 15);
    const int brow = wn + (lane & 15);
    const int ko = (lane >> 4) * 8;

    #define STAGE(buf, koff) do {                                              \
        gl16(gA0 + (koff), As0 + (buf) * (BM * 32) + wave * 512);              \
        if constexpr (BM == 128)                                               \
            gl16(gA0 + 64L * ldA + (koff),                                     \
                 As0 + (buf) * (BM * 32) + 2048 + wave * 512);                 \
        gl16(gB0 + (koff), Bs0 + (buf) * (BN * 32) + wave * 512);              \
        if constexpr (BN == 128)                                               \
            gl16(gB0 + 64L * K + (koff),                                       \
                 Bs0 + (buf) * (BN * 32) + 2048 + wave * 512);                 \
    } while (0)

    STAGE(0, 0);
    int cur = 0;
    for (int k0 = 0; k0 < K; k0 += 32) {
        __syncthreads();                       // drains vmcnt -> buf[cur] ready
        if (k0 + 32 < K) {                     // issue next tile early: latency
            if (cur) STAGE(0, k0 + 32);        //   hides under this tile's MFMA
            else     STAGE(1, k0 + 32);
        }
        h8 af[FM], bf[FN];
        #pragma unroll
        for (int i = 0; i < FM; ++i)
            af[i] = *(const h8*)&As0[cur * (BM * 32) + (arow + i * 16) * 32 + ko];
        #pragma unroll
        for (int j = 0; j < FN; ++j)
            bf[j] = *(const h8*)&Bs0[cur * (BN * 32) + (brow + j * 16) * 32 + ko];
        #pragma unroll
        for (int i = 0; i < FM; ++i)
            #pragma unroll
            for (int j = 0; j < FN; ++j)
                acc[i][j] = __builtin_amdgcn_mfma_f32_16x16x32_f16(af[i], bf[j], acc[i][j], 0, 0, 0);
        cur ^= 1;
    }
    #undef STAGE

    // epilogue: C/D layout col=lane&15, row=(lane>>4)*4+reg
    const int colc = lane & 15;
    const int rowb = (lane >> 4) * 4;
    constexpr int CPR = BN / 8;            // 8-u16 chunks per staged row
    constexpr int NCH = BM * BN / 8;       // total chunks

    if constexpr (EPI & 64) {
        const int seg = bn >> 8;          // 0=Q,1=K,2=E,3=V^T
        const int nb  = bn & 255;
        if (seg < 3) {
            u16* dst = (seg == 0) ? Ch : ((seg == 1) ? Ch2 : Ch3);
            __syncthreads();              // K-loop LDS reads done; reuse smem
            #pragma unroll
            for (int i = 0; i < FM; ++i)
                #pragma unroll
                for (int j = 0; j < FN; ++j) {
                    int cl = wn + j * 16 + colc;
                    #pragma unroll
                    for (int r = 0; r < 4; ++r)
                        smem[(wm + i * 16 + rowb + r) * BN + cl] = f2h(acc[i][j][r]);
                }
            __syncthreads();
            #pragma unroll
            for (int u = 0; u < NCH / 256; ++u) {
                int ch = t + u * 256;
                int rl = ch / CPR, c8 = ch % CPR;
                *(uint4*)&dst[(long)(bm + rl) * DD + nb + c8 * 8] =
                    *(const uint4*)&smem[rl * BN + c8 * 8];
            }
        } else {
            #pragma unroll
            for (int i = 0; i < FM; ++i) {
                int r0 = bm + wm + i * 16 + rowb;
                int b  = r0 >> 11;
                int m0 = r0 & (LL - 1);
                #pragma unroll
                for (int j = 0; j < FN; ++j) {
                    int nn = nb + wn + j * 16 + colc;
                    f32x4 v = acc[i][j];
                    ushort4 pk;
                    pk.x = f2h(v.x); pk.y = f2h(v.y); pk.z = f2h(v.z); pk.w = f2h(v.w);
                    *(ushort4*)&Ch4[((long)b * DD + nn) * LL + m0] = pk;
                }
            }
        }
    } else if constexpr (EPI & 128) {
        u16* dst = ((bn >= LL) ? Ch2 : Ch) + (long)bz * sC;
        const int nb = bn & (LL - 1);
        __syncthreads();                  // K-loop LDS reads done; reuse smem
        #pragma unroll
        for (int i = 0; i < FM; ++i)
            #pragma unroll
            for (int j = 0; j < FN; ++j) {
                int cl = wn + j * 16 + colc;
                #pragma unroll
                for (int r = 0; r < 4; ++r)
                    smem[(wm + i * 16 + rowb + r) * BN + cl] = f2h(acc[i][j][r]);
            }
        __syncthreads();
        #pragma unroll
        for (int u = 0; u < NCH / 256; ++u) {
            int ch = t + u * 256;
            int rl = ch / CPR, c8 = ch % CPR;
            *(uint4*)&dst[(long)(bm + rl) * LL + nb + c8 * 8] =
                *(const uint4*)&smem[rl * BN + c8 * 8];
        }
    } else if constexpr ((EPI & 16) && !(EPI & 8)) {
        // plain f16-out path (PV, FFN): compute val incl. bias/leaky/residual, stage, store
        __syncthreads();                  // K-loop LDS reads done; reuse smem
        #pragma unroll
        for (int i = 0; i < FM; ++i) {
            #pragma unroll
            for (int j = 0; j < FN; ++j) {
                int n = bn + wn + j * 16 + colc;
                float bv = (EPI & 1) ? bias[n] : 0.f;
                #pragma unroll
                for (int r = 0; r < 4; ++r) {
                    long row = bm + wm + i * 16 + rowb + r;
                    float val = acc[i][j][r] + bv;
                    if (EPI & 2) val = (val >= 0.f) ? val : 0.2f * val;
                    long off = row * (long)N + n;
                    if (EPI & 4)   val += Cres[off];
                    if (EPI & 256) val += h2f(CresH[off]);
                    smem[(wm + i * 16 + rowb + r) * BN + (wn + j * 16 + colc)] = f2h(val);
                }
            }
        }
        __syncthreads();
        #pragma unroll
        for (int u = 0; u < NCH / 256; ++u) {
            int ch = t + u * 256;
            int rl = ch / CPR, c8 = ch % CPR;
            *(uint4*)&Ch[(long)(bm + rl) * N + bn + c8 * 8] =
                *(const uint4*)&smem[rl * BN + c8 * 8];
        }
    } else {
        #pragma unroll
        for (int i = 0; i < FM; ++i) {
            #pragma unroll
            for (int j = 0; j < FN; ++j) {
                int n = bn + wn + j * 16 + colc;
                float bv = (EPI & 1) ? bias[n] : 0.f;
                #pragma unroll
                for (int r = 0; r < 4; ++r) {
                    long row = bm + wm + i * 16 + rowb + r;
                    float val = acc[i][j][r] + bv;
                    if (EPI & 2) val = (val >= 0.f) ? val : 0.2f * val;
                    long off = row * (long)N + n;
                    if (EPI & 4)   val += Cres[off];
                    if (EPI & 256) val += h2f(CresH[off]);
                    if (EPI & 8) Cf[off] = val;
                    if (EPI & 16) Ch[off] = f2h(val);
                }
            }
        }
    }
}

// ---------------- skew + scale + softmax; f16 in, f16 probs in place --------
__global__ __launch_bounds__(256)
void skew_softmax(u16* __restrict__ S1, const u16* __restrict__ QE)
{
    const int bi = blockIdx.x;
    const int b = bi >> 11;
    const int i = bi & (LL - 1);
    u16* srow = S1 + (long)bi * LL;
    const u16* qe_i  = QE + ((long)b * LL + i) * LL;
    const u16* qe_i1 = qe_i + ((i + 1 < LL) ? LL : 0);
    const int t = threadIdx.x;

    uint4 sv = ((const uint4*)srow)[t];      // elements m = t*8 .. t*8+7
    const u16* se = (const u16*)&sv;
    float vals[8];
    float mx = -1e30f;
    #pragma unroll
    for (int j = 0; j < 8; ++j) {
        int m = t * 8 + j;
        float srel;
        if (m <= i)            srel = h2f(qe_i[m - i + (LL - 1)]);
        else if (m == i + 1)   srel = 0.f;
        else                   srel = h2f(qe_i1[m - i - 2]);
        float s = (h2f(se[j]) + srel) * 0.125f;
        vals[j] = s;
        mx = fmaxf(mx, s);
    }
    #pragma unroll
    for (int off = 32; off >= 1; off >>= 1)
        mx = fmaxf(mx, __shfl_xor(mx, off, 64));
    __shared__ float redm[4], reds[4];
    const int wid = t >> 6;
    if ((t & 63) == 0) redm[wid] = mx;
    __syncthreads();
    mx = fmaxf(fmaxf(redm[0], redm[1]), fmaxf(redm[2], redm[3]));

    float sum = 0.f;
    #pragma unroll
    for (int j = 0; j < 8; ++j) { vals[j] = expf(vals[j] - mx); sum += vals[j]; }
    #pragma unroll
    for (int off = 32; off >= 1; off >>= 1)
        sum += __shfl_xor(sum, off, 64);
    if ((t & 63) == 0) reds[wid] = sum;
    __syncthreads();
    sum = reds[0] + reds[1] + reds[2] + reds[3];
    float inv = 1.0f / sum;
    uint4 ov;
    u16* oe = (u16*)&ov;
    #pragma unroll
    for (int j = 0; j < 8; ++j) oe[j] = f2h(vals[j] * inv);
    ((uint4*)srow)[t] = ov;
}

// ---------------- final classifier (x read as f16) ----------------
__global__ __launch_bounds__(960)
void fc_partial(const u16* __restrict__ xh, const float* __restrict__ W,
                float* __restrict__ part)
{
    const int v = threadIdx.x;
    const int b = threadIdx.y;
    const int chunk = blockIdx.x;
    const int KC = (int)(LD_ / 256); // 2048
    const long k0 = (long)chunk * KC;
    const u16* xb = xh + (long)b * LD_ + k0;
    const float* Wp = W + k0 * VV + v;
    float acc = 0.f;
    #pragma unroll 4
    for (int k2 = 0; k2 < KC; ++k2)
        acc = fmaf(h2f(xb[k2]), Wp[(long)k2 * VV], acc);
    part[((long)chunk * BB + b) * VV + v] = acc;
}

__global__ __launch_bounds__(960)
void fc_finish(const float* __restrict__ part, const float* __restrict__ bias,
               float* __restrict__ out)
{
    const int v = threadIdx.x, b = threadIdx.y;
    float acc = bias[v];
    for (int c = 0; c < 256; ++c)
        acc += part[((long)c * BB + b) * VV + v];
    __shared__ float lds[BB][VV];
    __shared__ float mxs[BB], sms[BB];
    lds[b][v] = acc;
    __syncthreads();
    if (v == 0) {
        float m = -1e30f;
        for (int j = 0; j < VV; ++j) m = fmaxf(m, lds[b][j]);
        float s = 0.f;
        for (int j = 0; j < VV; ++j) s += expf(lds[b][j] - m);
        mxs[b] = m; sms[b] = s;
    }
    __syncthreads();
    out[b * VV + v] = expf(lds[b][v] - mxs[b]) / sms[b];
}

// ---------------- driver ----------------
extern "C" void kernel_launch(void* const* d_in, const int* in_sizes, int n_in,
                              void* d_out, int out_size, void* d_ws, size_t ws_size,
                              hipStream_t stream)
{
    const int*   tokens = (const int*)d_in[0];
    const float* table  = (const float*)d_in[1];
    const float* Wq1 = (const float*)d_in[2];
    const float* Wk1 = (const float*)d_in[3];
    const float* Wv1 = (const float*)d_in[4];
    const float* Wq2 = (const float*)d_in[5];
    const float* Wk2 = (const float*)d_in[6];
    const float* Wv2 = (const float*)d_in[7];
    const float* Wf1 = (const float*)d_in[8];
    const float* bf1 = (const float*)d_in[9];
    const float* Wf2 = (const float*)d_in[10];
    const float* bf2 = (const float*)d_in[11];
    const float* Wfc = (const float*)d_in[12];
    const float* bfc = (const float*)d_in[13];

    char* p = (char*)d_ws;
    u16* xh = (u16*)p;     p += BLD * 2;        // f16 residual stream
    u16* qb = (u16*)p;     p += BLD * 2;
    u16* kb = (u16*)p;     p += BLD * 2;
    u16* eb = (u16*)p;     p += BLD * 2;        // E = K - Q (from folded weights)
    u16* vt = (u16*)p;     p += BLD * 2;        // [B][D][L]
    u16* S1 = (u16*)p;     p += BLL * 2;        // f16 scores -> probs in place
    u16* QE = (u16*)p;     p += BLL * 2;
    u16* qkevw = (u16*)p;  p += 12L * 4 * 65536 * 2;  // [(h*6+l)][4][256][256] (Q,K,E,V)
    u16* fw = (u16*)p;     p += 12L * 65536 * 2;      // [f1:6][f2:6][256][256]
    float* pe = (float*)p; p += LD_ * 4;
    float* part = (float*)p;
    u16* hb = qb;                               // FFN hidden aliases Q buffer

    // merged weight conversion (1 dispatch): QKEV interleaved per (half,layer)
    const long LS = 4 * 65536;
    WcArgs wa;
    wa.src[0] = Wq1; wa.sub[0] = nullptr; wa.dst[0] = qkevw + 0L * 65536;  wa.lstride[0] = LS;
    wa.src[1] = Wk1; wa.sub[1] = nullptr; wa.dst[1] = qkevw + 1L * 65536;  wa.lstride[1] = LS;
    wa.src[2] = Wk1; wa.sub[2] = Wq1;     wa.dst[2] = qkevw + 2L * 65536;  wa.lstride[2] = LS;
    wa.src[3] = Wv1; wa.sub[3] = nullptr; wa.dst[3] = qkevw + 3L * 65536;  wa.lstride[3] = LS;
    wa.src[4] = Wq2; wa.sub[4] = nullptr; wa.dst[4] = qkevw + 24L * 65536; wa.lstride[4] = LS;
    wa.src[5] = Wk2; wa.sub[5] = nullptr; wa.dst[5] = qkevw + 24L * 65536 + 1 * 65536; wa.lstride[5] = LS;
    wa.src[6] = Wk2; wa.sub[6] = Wq2;     wa.dst[6] = qkevw + 24L * 65536 + 2 * 65536; wa.lstride[6] = LS;
    wa.src[7] = Wv2; wa.sub[7] = nullptr; wa.dst[7] = qkevw + 24L * 65536 + 3 * 65536; wa.lstride[7] = LS;
    wa.src[8] = Wf1; wa.sub[8] = nullptr; wa.dst[8] = fw;                  wa.lstride[8] = 65536;
    wa.src[9] = Wf2; wa.sub[9] = nullptr; wa.dst[9] = fw + 6L * 65536;     wa.lstride[9] = 65536;
    wconv_all<<<3840, 256, 0, stream>>>(wa);

    pe_kernel<<<(int)(LD_ / 256), 256, 0, stream>>>(pe);
    embed_kernel<<<(int)((BLD + 255) / 256), 256, 0, stream>>>(tokens, table, pe, xh);

    const dim3 gqkev(8, 64, 1);       // 8192 x 1024, 128x128 tiles (512 blocks)
    const dim3 gscore(32, 16, BB);    // 2048 x 4096(dual), 128x128 tiles (2048 blocks)
    const dim3 gpv(2, 32, BB);        // 2048 x 256, 64x128 tiles (256 blocks)
    const dim3 gffn(2, 128, 1);       // 8192 x 256, 64x128 tiles (256 blocks)

    for (int layer = 0; layer < NLAYERS; ++layer) {
        for (int half = 0; half < 2; ++half) {
            const u16* wqkev = qkevw + ((long)(half * 6 + layer)) * LS;
            // fused QKEV projection: Q,K,E row-major; V transposed
            gemm_mfma<64, 128, 128><<<gqkev, 256, 0, stream>>>(
                xh, wqkev, nullptr, nullptr, nullptr, nullptr, qb, kb, eb, vt,
                BB * LL, 1024, DD, DD, 0, 0, 0);
            // S1 = Q K^T and QE = Q E^T in one dispatch (f16 out)
            gemm_mfma<128, 128, 128><<<gscore, 256, 0, stream>>>(
                qb, kb, eb, nullptr, nullptr, nullptr, S1, QE, nullptr, nullptr,
                LL, LL, DD, DD, LD_, LD_, LxL);
            // probs = softmax((S1 + skew(QE))/8) in place
            skew_softmax<<<BB * LL, 256, 0, stream>>>(S1, QE);
            // xh = probs @ V + xh   (f16 residual, 64x128 tiles)
            gemm_mfma<256 | 16, 64, 128><<<gpv, 256, 0, stream>>>(
                S1, vt, nullptr, nullptr, (const float*)xh, nullptr, xh,
                nullptr, nullptr, nullptr,
                LL, DD, LL, LL, LxL, LD_, LD_);
        }
        // FFN (64x128 tiles): h = leaky(xh@Wf1+b1); xh = h@Wf2+b2
        gemm_mfma<1 | 2 | 16, 64, 128><<<gffn, 256, 0, stream>>>(
            xh, fw + (long)layer * 65536, nullptr, bf1 + layer * DD, nullptr,
            nullptr, hb, nullptr, nullptr, nullptr, BB * LL, DD, DD, DD, 0, 0, 0);
        gemm_mfma<1 | 16, 64, 128><<<gffn, 256, 0, stream>>>(
            hb, fw + (long)(6 + layer) * 65536, nullptr, bf2 + layer * DD, nullptr,
            nullptr, xh, nullptr, nullptr, nullptr, BB * LL, DD, DD, DD, 0, 0, 0);
    }

    fc_partial<<<256, dim3(VV, BB, 1), 0, stream>>>(xh, Wfc, part);
    fc_finish<<<1, dim3(VV, BB, 1), 0, stream>>>(part, bfc, (float*)d_out);
}

// Round 17
// 1615.641 us; speedup vs baseline: 1.0105x; 1.0105x over previous
//
#include <hip/hip_runtime.h>
#include <hip/hip_fp16.h>

typedef unsigned short u16;
typedef unsigned int   u32;

#define BB 4
#define LL 2048
#define DD 256
#define VV 240
#define NLAYERS 6

static constexpr long BLD = (long)BB * LL * DD;   // 2,097,152
static constexpr long LD_ = (long)LL * DD;        // 524,288
static constexpr long LxL = (long)LL * LL;        // 4,194,304
static constexpr long BLL = (long)BB * LxL;       // 16,777,216

typedef _Float16 h8  __attribute__((ext_vector_type(8)));   // MFMA A/B fragment
typedef float  f32x4 __attribute__((ext_vector_type(4)));

__device__ __forceinline__ u16 f2h(float f) {
    _Float16 h = (_Float16)f;
    return __builtin_bit_cast(u16, h);
}
__device__ __forceinline__ float h2f(u16 u) {
    return (float)__builtin_bit_cast(_Float16, u);
}

__device__ __forceinline__ void gl16(const void* g, void* l) {
    __builtin_amdgcn_global_load_lds((const __attribute__((address_space(1))) void*)g,
                                     (__attribute__((address_space(3))) void*)l, 16, 0, 0);
}

// XCD-aware bijective block remap (requires total blocks % 8 == 0).
__device__ __forceinline__ uint3 swz_bid() {
    const int gx = gridDim.x, gy = gridDim.y;
    const int nwg = gx * gy * gridDim.z;
    const int lin = blockIdx.x + gx * (blockIdx.y + gy * blockIdx.z);
    const int q = nwg >> 3;
    const int swz = (lin & 7) * q + (lin >> 3);
    uint3 r;
    r.x = swz % gx;
    const int t2 = swz / gx;
    r.y = t2 % gy;
    r.z = t2 / gy;
    return r;
}

// ---------------- positional encoding precompute: pe[l][i] (batch-independent) ----------------
__global__ __launch_bounds__(256)
void pe_kernel(float* __restrict__ pe)
{
    int idx = blockIdx.x * 256 + threadIdx.x;     // l*DD + i, 524288 total
    int i = idx & (DD - 1);
    int l = idx >> 8;
    float base = (float)l * 1e-5f;
    float p = powf(base, (float)i * (1.0f / (float)DD));
    float ang = p - ((i & 1) ? 0.0f : 1.57079632679489662f);
    pe[idx] = sinf(ang);
}

// ---------------- embedding + pe add (f16 residual stream only) ----------------
__global__ __launch_bounds__(256)
void embed_kernel(const int* __restrict__ tokens, const float* __restrict__ table,
                  const float* __restrict__ pe, u16* __restrict__ xh)
{
    long idx = (long)blockIdx.x * 256 + threadIdx.x;
    if (idx >= BLD) return;
    int i  = (int)(idx & (DD - 1));
    long bl = idx >> 8;
    int l  = (int)(bl & (LL - 1));
    int tok = tokens[bl];
    float v = table[(long)tok * DD + i] + pe[(long)l * DD + i];
    xh[idx] = f2h(v);
}

// ---- merged weight convert+transpose (ALL 10 matrices in one dispatch) ----
// dst[m*lstride + n*256 + k] = f16(W[m][k][n] - Wsub[m][k][n])
struct WcArgs {
    const float* src[10];
    const float* sub[10];       // nullptr -> no subtraction
    u16*         dst[10];
    long         lstride[10];
};

__global__ __launch_bounds__(256)
void wconv_all(WcArgs a)
{
    int blk = blockIdx.x;            // 10 mats * 6 layers * 64 tiles = 3840
    int which = blk / 384;
    int rest  = blk % 384;
    int m  = rest >> 6;
    int ti = (rest >> 3) & 7;        // k tile
    int tj = rest & 7;               // n tile
    const float* src = a.src[which] + (long)m * 65536;
    const float* sub = a.sub[which];
    u16* dst = a.dst[which] + (long)m * a.lstride[which];
    __shared__ float tile[32][33];
    int t = threadIdx.x;
    int c = t & 31, r8 = t >> 5;
    #pragma unroll
    for (int p = 0; p < 4; ++p) {
        int r = r8 + p * 8;
        long off = (long)(ti * 32 + r) * 256 + tj * 32 + c;
        float v = src[off];
        if (sub) v -= sub[(long)m * 65536 + off];
        tile[r][c] = v;
    }
    __syncthreads();
    #pragma unroll
    for (int p = 0; p < 4; ++p) {
        int n = r8 + p * 8;
        dst[(long)(tj * 32 + n) * 256 + ti * 32 + c] = f2h(tile[c][n]);
    }
}

// ---------------- f16 MFMA GEMM, 2-phase double-buffered pipeline (r7-proven) ----------------
// C[M,N] = A[M,K] (row pitch ldA) * B^T  (B stored [N][K], pitch K)
// EPI bits: 1=+bias[n](f32)  2=leaky(0.2)  4=+Cres(f32)  8=write Cf(f32)  16=write Ch(f16)
//   64 = QKEV quad-output: col seg 0->Ch(Q), 1->Ch2(K), 2->Ch3(E), 3->Ch4(V transposed [b][d][l])
//  128 = dual score: bn<2048 uses B  -> Ch(S1);  bn>=2048 uses B2 -> Ch2(QE); pitch LL
//  256 = +residual from f16 buffer (Cres reinterpreted as u16*)
template<int EPI, int BM, int BN>
__global__ __launch_bounds__(256)
void gemm_mfma(const u16* __restrict__ A, const u16* __restrict__ B,
               const u16* __restrict__ B2,
               const float* __restrict__ bias, const float* __restrict__ Cres,
               float* __restrict__ Cf, u16* __restrict__ Ch,
               u16* __restrict__ Ch2, u16* __restrict__ Ch3, u16* __restrict__ Ch4,
               int M, int N, int K, int ldA,
               long sA, long sB, long sC)
{
    constexpr int FM = BM / 32, FN = BN / 32;
    __shared__ u16 As[2][BM * 32];
    __shared__ u16 Bs[2][BN * 32];
    const uint3 bid = swz_bid();           // XCD-contiguous tile chunks (T1)
    const int bz = bid.z;
    A += (long)bz * sA;
    const int bm = bid.y * BM;
    const int bn = bid.x * BN;
    int bnb = bn;                    // column index for B addressing
    const u16* Bp;
    if constexpr (EPI & 128) {
        Bp = (bn >= LL) ? B2 : B;
        if (bn >= LL) bnb = bn - LL;
        Bp += (long)bz * sB;
    } else {
        Bp = B + (long)bz * sB;
    }
    const u16* CresH = (const u16*)Cres;
    if constexpr (EPI & 4)   Cres  += (long)bz * sC;
    if constexpr (EPI & 256) CresH += (long)bz * sC;
    if constexpr (EPI & 8)   Cf    += (long)bz * sC;
    if constexpr ((EPI & 16) && !(EPI & (64 | 128))) Ch += (long)bz * sC;

    const int t = threadIdx.x;
    const int lane = t & 63, wave = t >> 6;
    const int wm = (wave >> 1) * (BM / 2), wn = (wave & 1) * (BN / 2);

    f32x4 acc[FM][FN];
    #pragma unroll
    for (int i = 0; i < FM; ++i)
        #pragma unroll
        for (int j = 0; j < FN; ++j)
            acc[i][j] = (f32x4){0.f, 0.f, 0.f, 0.f};

    const u16* gA0 = A  + (long)(bm  + (t >> 2)) * ldA + (t & 3) * 8;
    const u16* gB0 = Bp + (long)(bnb + (t >> 2)) * K   + (t & 3) * 8;

    const int arow = wm + (lane & 15);
    const int brow = wn + (lane & 15);
    const int ko = (lane >> 4) * 8;

    #define STAGE(buf, koff) do {                                              \
        gl16(gA0 + (koff), &As[buf][wave * 512]);                              \
        if constexpr (BM == 128) gl16(gA0 + 64L * ldA + (koff),                \
                                      &As[buf][2048 + wave * 512]);            \
        gl16(gB0 + (koff), &Bs[buf][wave * 512]);                              \
        if constexpr (BN == 128) gl16(gB0 + 64L * K + (koff),                  \
                                      &Bs[buf][2048 + wave * 512]);            \
    } while (0)

    STAGE(0, 0);
    int cur = 0;
    for (int k0 = 0; k0 < K; k0 += 32) {
        __syncthreads();                       // drains vmcnt -> buf[cur] ready
        if (k0 + 32 < K) {                     // issue next tile early: latency
            if (cur) STAGE(0, k0 + 32);        //   hides under this tile's MFMA
            else     STAGE(1, k0 + 32);
        }
        h8 af[FM], bf[FN];
        #pragma unroll
        for (int i = 0; i < FM; ++i) af[i] = *(const h8*)&As[cur][(arow + i * 16) * 32 + ko];
        #pragma unroll
        for (int j = 0; j < FN; ++j) bf[j] = *(const h8*)&Bs[cur][(brow + j * 16) * 32 + ko];
        #pragma unroll
        for (int i = 0; i < FM; ++i)
            #pragma unroll
            for (int j = 0; j < FN; ++j)
                acc[i][j] = __builtin_amdgcn_mfma_f32_16x16x32_f16(af[i], bf[j], acc[i][j], 0, 0, 0);
        cur ^= 1;
    }
    #undef STAGE

    // epilogue: C/D layout col=lane&15, row=(lane>>4)*4+reg  (direct stores, r15-proven)
    const int colc = lane & 15;
    const int rowb = (lane >> 4) * 4;
    if constexpr (EPI & 64) {
        const int seg = bn >> 8;          // 0=Q,1=K,2=E,3=V^T
        const int nb  = bn & 255;
        if (seg < 3) {
            u16* dst = (seg == 0) ? Ch : ((seg == 1) ? Ch2 : Ch3);
            #pragma unroll
            for (int i = 0; i < FM; ++i)
                #pragma unroll
                for (int j = 0; j < FN; ++j) {
                    int nn = nb + wn + j * 16 + colc;
                    #pragma unroll
                    for (int r = 0; r < 4; ++r) {
                        long row = bm + wm + i * 16 + rowb + r;
                        dst[row * DD + nn] = f2h(acc[i][j][r]);
                    }
                }
        } else {
            #pragma unroll
            for (int i = 0; i < FM; ++i) {
                int r0 = bm + wm + i * 16 + rowb;
                int b  = r0 >> 11;
                int m0 = r0 & (LL - 1);
                #pragma unroll
                for (int j = 0; j < FN; ++j) {
                    int nn = nb + wn + j * 16 + colc;
                    f32x4 v = acc[i][j];
                    ushort4 pk;
                    pk.x = f2h(v.x); pk.y = f2h(v.y); pk.z = f2h(v.z); pk.w = f2h(v.w);
                    *(ushort4*)&Ch4[((long)b * DD + nn) * LL + m0] = pk;
                }
            }
        }
    } else if constexpr (EPI & 128) {
        u16* dst = ((bn >= LL) ? Ch2 : Ch) + (long)bz * sC;
        const int nb = bn & (LL - 1);
        #pragma unroll
        for (int i = 0; i < FM; ++i)
            #pragma unroll
            for (int j = 0; j < FN; ++j) {
                int n = nb + wn + j * 16 + colc;
                #pragma unroll
                for (int r = 0; r < 4; ++r) {
                    long row = bm + wm + i * 16 + rowb + r;
                    dst[row * LL + n] = f2h(acc[i][j][r]);
                }
            }
    } else {
        #pragma unroll
        for (int i = 0; i < FM; ++i) {
            #pragma unroll
            for (int j = 0; j < FN; ++j) {
                int n = bn + wn + j * 16 + colc;
                float bv = (EPI & 1) ? bias[n] : 0.f;
                #pragma unroll
                for (int r = 0; r < 4; ++r) {
                    long row = bm + wm + i * 16 + rowb + r;
                    float val = acc[i][j][r] + bv;
                    if (EPI & 2) val = (val >= 0.f) ? val : 0.2f * val;
                    long off = row * (long)N + n;
                    if (EPI & 4)   val += Cres[off];
                    if (EPI & 256) val += h2f(CresH[off]);
                    if (EPI & 8) Cf[off] = val;
                    if (EPI & 16) Ch[off] = f2h(val);
                }
            }
        }
    }
}

// ---------------- skew + scale + softmax; f16 in, f16 probs in place --------
__global__ __launch_bounds__(256)
void skew_softmax(u16* __restrict__ S1, const u16* __restrict__ QE)
{
    const int bi = blockIdx.x;
    const int b = bi >> 11;
    const int i = bi & (LL - 1);
    u16* srow = S1 + (long)bi * LL;
    const u16* qe_i  = QE + ((long)b * LL + i) * LL;
    const u16* qe_i1 = qe_i + ((i + 1 < LL) ? LL : 0);
    const int t = threadIdx.x;

    uint4 sv = ((const uint4*)srow)[t];      // elements m = t*8 .. t*8+7
    const u16* se = (const u16*)&sv;
    float vals[8];
    float mx = -1e30f;
    #pragma unroll
    for (int j = 0; j < 8; ++j) {
        int m = t * 8 + j;
        float srel;
        if (m <= i)            srel = h2f(qe_i[m - i + (LL - 1)]);
        else if (m == i + 1)   srel = 0.f;
        else                   srel = h2f(qe_i1[m - i - 2]);
        float s = (h2f(se[j]) + srel) * 0.125f;
        vals[j] = s;
        mx = fmaxf(mx, s);
    }
    #pragma unroll
    for (int off = 32; off >= 1; off >>= 1)
        mx = fmaxf(mx, __shfl_xor(mx, off, 64));
    __shared__ float redm[4], reds[4];
    const int wid = t >> 6;
    if ((t & 63) == 0) redm[wid] = mx;
    __syncthreads();
    mx = fmaxf(fmaxf(redm[0], redm[1]), fmaxf(redm[2], redm[3]));

    float sum = 0.f;
    #pragma unroll
    for (int j = 0; j < 8; ++j) { vals[j] = expf(vals[j] - mx); sum += vals[j]; }
    #pragma unroll
    for (int off = 32; off >= 1; off >>= 1)
        sum += __shfl_xor(sum, off, 64);
    if ((t & 63) == 0) reds[wid] = sum;
    __syncthreads();
    sum = reds[0] + reds[1] + reds[2] + reds[3];
    float inv = 1.0f / sum;
    uint4 ov;
    u16* oe = (u16*)&ov;
    #pragma unroll
    for (int j = 0; j < 8; ++j) oe[j] = f2h(vals[j] * inv);
    ((uint4*)srow)[t] = ov;
}

// ---------------- final classifier (x read as f16) ----------------
__global__ __launch_bounds__(960)
void fc_partial(const u16* __restrict__ xh, const float* __restrict__ W,
                float* __restrict__ part)
{
    const int v = threadIdx.x;
    const int b = threadIdx.y;
    const int chunk = blockIdx.x;
    const int KC = (int)(LD_ / 256); // 2048
    const long k0 = (long)chunk * KC;
    const u16* xb = xh + (long)b * LD_ + k0;
    const float* Wp = W + k0 * VV + v;
    float acc = 0.f;
    #pragma unroll 4
    for (int k2 = 0; k2 < KC; ++k2)
        acc = fmaf(h2f(xb[k2]), Wp[(long)k2 * VV], acc);
    part[((long)chunk * BB + b) * VV + v] = acc;
}

__global__ __launch_bounds__(960)
void fc_finish(const float* __restrict__ part, const float* __restrict__ bias,
               float* __restrict__ out)
{
    const int v = threadIdx.x, b = threadIdx.y;
    float acc = bias[v];
    for (int c = 0; c < 256; ++c)
        acc += part[((long)c * BB + b) * VV + v];
    __shared__ float lds[BB][VV];
    __shared__ float mxs[BB], sms[BB];
    lds[b][v] = acc;
    __syncthreads();
    if (v == 0) {
        float m = -1e30f;
        for (int j = 0; j < VV; ++j) m = fmaxf(m, lds[b][j]);
        float s = 0.f;
        for (int j = 0; j < VV; ++j) s += expf(lds[b][j] - m);
        mxs[b] = m; sms[b] = s;
    }
    __syncthreads();
    out[b * VV + v] = expf(lds[b][v] - mxs[b]) / sms[b];
}

// ---------------- driver ----------------
extern "C" void kernel_launch(void* const* d_in, const int* in_sizes, int n_in,
                              void* d_out, int out_size, void* d_ws, size_t ws_size,
                              hipStream_t stream)
{
    const int*   tokens = (const int*)d_in[0];
    const float* table  = (const float*)d_in[1];
    const float* Wq1 = (const float*)d_in[2];
    const float* Wk1 = (const float*)d_in[3];
    const float* Wv1 = (const float*)d_in[4];
    const float* Wq2 = (const float*)d_in[5];
    const float* Wk2 = (const float*)d_in[6];
    const float* Wv2 = (const float*)d_in[7];
    const float* Wf1 = (const float*)d_in[8];
    const float* bf1 = (const float*)d_in[9];
    const float* Wf2 = (const float*)d_in[10];
    const float* bf2 = (const float*)d_in[11];
    const float* Wfc = (const float*)d_in[12];
    const float* bfc = (const float*)d_in[13];

    char* p = (char*)d_ws;
    u16* xh = (u16*)p;     p += BLD * 2;        // f16 residual stream
    u16* qb = (u16*)p;     p += BLD * 2;
    u16* kb = (u16*)p;     p += BLD * 2;
    u16* eb = (u16*)p;     p += BLD * 2;        // E = K - Q (from folded weights)
    u16* vt = (u16*)p;     p += BLD * 2;        // [B][D][L]
    u16* S1 = (u16*)p;     p += BLL * 2;        // f16 scores -> probs in place
    u16* QE = (u16*)p;     p += BLL * 2;
    u16* qkevw = (u16*)p;  p += 12L * 4 * 65536 * 2;  // [(h*6+l)][4][256][256] (Q,K,E,V)
    u16* fw = (u16*)p;     p += 12L * 65536 * 2;      // [f1:6][f2:6][256][256]
    float* pe = (float*)p; p += LD_ * 4;
    float* part = (float*)p;
    u16* hb = qb;                               // FFN hidden aliases Q buffer

    // merged weight conversion (1 dispatch): QKEV interleaved per (half,layer)
    const long LS = 4 * 65536;
    WcArgs wa;
    wa.src[0] = Wq1; wa.sub[0] = nullptr; wa.dst[0] = qkevw + 0L * 65536;  wa.lstride[0] = LS;
    wa.src[1] = Wk1; wa.sub[1] = nullptr; wa.dst[1] = qkevw + 1L * 65536;  wa.lstride[1] = LS;
    wa.src[2] = Wk1; wa.sub[2] = Wq1;     wa.dst[2] = qkevw + 2L * 65536;  wa.lstride[2] = LS;
    wa.src[3] = Wv1; wa.sub[3] = nullptr; wa.dst[3] = qkevw + 3L * 65536;  wa.lstride[3] = LS;
    wa.src[4] = Wq2; wa.sub[4] = nullptr; wa.dst[4] = qkevw + 24L * 65536; wa.lstride[4] = LS;
    wa.src[5] = Wk2; wa.sub[5] = nullptr; wa.dst[5] = qkevw + 24L * 65536 + 1 * 65536; wa.lstride[5] = LS;
    wa.src[6] = Wk2; wa.sub[6] = Wq2;     wa.dst[6] = qkevw + 24L * 65536 + 2 * 65536; wa.lstride[6] = LS;
    wa.src[7] = Wv2; wa.sub[7] = nullptr; wa.dst[7] = qkevw + 24L * 65536 + 3 * 65536; wa.lstride[7] = LS;
    wa.src[8] = Wf1; wa.sub[8] = nullptr; wa.dst[8] = fw;                  wa.lstride[8] = 65536;
    wa.src[9] = Wf2; wa.sub[9] = nullptr; wa.dst[9] = fw + 6L * 65536;     wa.lstride[9] = 65536;
    wconv_all<<<3840, 256, 0, stream>>>(wa);

    pe_kernel<<<(int)(LD_ / 256), 256, 0, stream>>>(pe);
    embed_kernel<<<(int)((BLD + 255) / 256), 256, 0, stream>>>(tokens, table, pe, xh);

    const dim3 gqkev(8, 64, 1);       // 8192 x 1024, 128x128 tiles (512 blocks)
    const dim3 gscore(32, 16, BB);    // 2048 x 4096(dual), 128x128 tiles (2048 blocks)
    const dim3 gpv(2, 32, BB);        // 2048 x 256, 64x128 tiles (256 blocks)
    const dim3 gffn(2, 128, 1);       // 8192 x 256, 64x128 tiles (256 blocks)

    for (int layer = 0; layer < NLAYERS; ++layer) {
        for (int half = 0; half < 2; ++half) {
            const u16* wqkev = qkevw + ((long)(half * 6 + layer)) * LS;
            // fused QKEV projection: Q,K,E row-major; V transposed
            gemm_mfma<64, 128, 128><<<gqkev, 256, 0, stream>>>(
                xh, wqkev, nullptr, nullptr, nullptr, nullptr, qb, kb, eb, vt,
                BB * LL, 1024, DD, DD, 0, 0, 0);
            // S1 = Q K^T and QE = Q E^T in one dispatch (f16 out)
            gemm_mfma<128, 128, 128><<<gscore, 256, 0, stream>>>(
                qb, kb, eb, nullptr, nullptr, nullptr, S1, QE, nullptr, nullptr,
                LL, LL, DD, DD, LD_, LD_, LxL);
            // probs = softmax((S1 + skew(QE))/8) in place
            skew_softmax<<<BB * LL, 256, 0, stream>>>(S1, QE);
            // xh = probs @ V + xh   (f16 residual, 64x128 tiles)
            gemm_mfma<256 | 16, 64, 128><<<gpv, 256, 0, stream>>>(
                S1, vt, nullptr, nullptr, (const float*)xh, nullptr, xh,
                nullptr, nullptr, nullptr,
                LL, DD, LL, LL, LxL, LD_, LD_);
        }
        // FFN (64x128 tiles): h = leaky(xh@Wf1+b1); xh = h@Wf2+b2
        gemm_mfma<1 | 2 | 16, 64, 128><<<gffn, 256, 0, stream>>>(
            xh, fw + (long)layer * 65536, nullptr, bf1 + layer * DD, nullptr,
            nullptr, hb, nullptr, nullptr, nullptr, BB * LL, DD, DD, DD, 0, 0, 0);
        gemm_mfma<1 | 16, 64, 128><<<gffn, 256, 0, stream>>>(
            hb, fw + (long)(6 + layer) * 65536, nullptr, bf2 + layer * DD, nullptr,
            nullptr, xh, nullptr, nullptr, nullptr, BB * LL, DD, DD, DD, 0, 0, 0);
    }

    fc_partial<<<256, dim3(VV, BB, 1), 0, stream>>>(xh, Wfc, part);
    fc_finish<<<1, dim3(VV, BB, 1), 0, stream>>>(part, bfc, (float*)d_out);
}